// Round 1
// baseline (91.191 us; speedup 1.0000x reference)
//
#include <hip/hip_runtime.h>

// Problem constants (B=16, N=128, H=16, S=20, ET=16)
#define NN      128
#define HH      16
#define SS      20
#define NP1     129
#define PLANE   (129 * 129)          // 16641
#define E_TOTAL (16 * 128 * 128)     // 262144
#define TSTRIDE 20                   // padded row stride (floats): 16B-aligned rows, <=2-way bank aliasing
#define EDGE_BLOCKS   1024           // E_TOTAL / 256
#define BORDER_BLOCKS 257            // 256 (b,h) pairs * 257 elems / 256 threads

// Kernel A: T[d][t][h] = sum_k edge_W[t][k] * dis_W[(d*16+k)*16 + h]
__global__ __launch_bounds__(256) void table_kernel(const float* __restrict__ edge_W,
                                                    const float* __restrict__ dis_W,
                                                    float* __restrict__ T) {
    int tid = blockIdx.x * 256 + threadIdx.x;   // 5120 threads
    if (tid >= SS * 16 * 16) return;
    int d = tid >> 8;
    int t = (tid >> 4) & 15;
    int h = tid & 15;
    const float* ew = edge_W + t * 16;
    const float* dw = dis_W + (d * 16) * 16 + h;
    float s = 0.f;
#pragma unroll
    for (int k = 0; k < 16; ++k) s = fmaf(ew[k], dw[k * 16], s);
    T[(d * 16 + t) * TSTRIDE + h] = s;
}

// Kernel B: edge blocks [0,1024) compute interior bias; blocks [1024,1281) fill token borders.
__global__ __launch_bounds__(256) void bias_kernel(const int* __restrict__ spatial_types,
                                                   const int* __restrict__ spt,       // [E,20]
                                                   const float* __restrict__ spatial_W, // [21,16]
                                                   const float* __restrict__ graph_token, // [16]
                                                   const float* __restrict__ T,       // [20*16*TSTRIDE]
                                                   float* __restrict__ out) {
    __shared__ float Tl[SS * 16 * TSTRIDE];     // 6400 floats = 25.6 KB
    const int tid = threadIdx.x;

    if (blockIdx.x < EDGE_BLOCKS) {
        // Stage the (d,t,h) table into LDS: 1600 float4s per block (L2-hot source).
        {
            float4* dst = (float4*)Tl;
            const float4* src = (const float4*)T;
#pragma unroll
            for (int j = 0; j < 7; ++j) {
                int i = tid + j * 256;
                if (i < (SS * 16 * TSTRIDE) / 4) dst[i] = src[i];
            }
        }
        __syncthreads();

        const int e   = blockIdx.x * 256 + tid;     // < E_TOTAL exactly
        const int g   = e >> 14;                    // / (128*128)
        const int rem = e & 16383;
        const int ls  = rem >> 7;
        const int lt  = rem & 127;

        const int st = spatial_types[e];

        float acc[16];
#pragma unroll
        for (int h = 0; h < 16; ++h) acc[h] = 0.f;

        // 20 path types: 5 x int4 loads (row is 80B, 16B-aligned).
        const int4* sp = (const int4*)(spt + (size_t)e * 20);

        auto step = [&](int d, int t) {
            const float* r = &Tl[(d * 16 + t) * TSTRIDE];
            float4 v0 = *(const float4*)(r);
            float4 v1 = *(const float4*)(r + 4);
            float4 v2 = *(const float4*)(r + 8);
            float4 v3 = *(const float4*)(r + 12);
            acc[0]  += v0.x; acc[1]  += v0.y; acc[2]  += v0.z; acc[3]  += v0.w;
            acc[4]  += v1.x; acc[5]  += v1.y; acc[6]  += v1.z; acc[7]  += v1.w;
            acc[8]  += v2.x; acc[9]  += v2.y; acc[10] += v2.z; acc[11] += v2.w;
            acc[12] += v3.x; acc[13] += v3.y; acc[14] += v3.z; acc[15] += v3.w;
        };

#pragma unroll
        for (int j = 0; j < 5; ++j) {
            int4 tt = sp[j];
            step(j * 4 + 0, tt.x);
            step(j * 4 + 1, tt.y);
            step(j * 4 + 2, tt.z);
            step(j * 4 + 3, tt.w);
        }

        const float inv = 1.0f / fmaxf((float)st, 1.0f);
        const float4* sw4 = (const float4*)(spatial_W + st * 16);
        const size_t base = (size_t)(g * 16) * PLANE + (size_t)(ls + 1) * NP1 + (size_t)(lt + 1);

#pragma unroll
        for (int q = 0; q < 4; ++q) {
            float4 s = sw4[q];
            out[base + (size_t)(q * 4 + 0) * PLANE] = fmaf(inv, acc[q * 4 + 0], s.x);
            out[base + (size_t)(q * 4 + 1) * PLANE] = fmaf(inv, acc[q * 4 + 1], s.y);
            out[base + (size_t)(q * 4 + 2) * PLANE] = fmaf(inv, acc[q * 4 + 2], s.z);
            out[base + (size_t)(q * 4 + 3) * PLANE] = fmaf(inv, acc[q * 4 + 3], s.w);
        }
    } else {
        // Border fill: 256 (b,h) planes, 257 elements each (row 0 full + col 0 rows 1..128).
        int idx = (blockIdx.x - EDGE_BLOCKS) * 256 + tid;   // < 65792 exactly
        unsigned pair = (unsigned)idx / 257u;
        unsigned r    = (unsigned)idx - pair * 257u;
        float v = graph_token[pair & 15u];
        size_t o = (size_t)pair * PLANE;
        if (r < 129u) out[o + r] = v;                       // row 0
        else          out[o + (size_t)(r - 128u) * NP1] = v; // col 0, rows 1..128
    }
}

extern "C" void kernel_launch(void* const* d_in, const int* in_sizes, int n_in,
                              void* d_out, int out_size, void* d_ws, size_t ws_size,
                              hipStream_t stream) {
    const int*   spatial_types = (const int*)d_in[0];
    const int*   spt           = (const int*)d_in[1];   // shortest_path_types [E,20]
    // d_in[2] graph_index, d_in[3] batch: structurally all-pairs — not needed.
    const float* spatial_W     = (const float*)d_in[4]; // [21,16]
    const float* edge_W        = (const float*)d_in[5]; // [16,16]
    const float* dis_W         = (const float*)d_in[6]; // [20*16*16]
    const float* graph_token   = (const float*)d_in[7]; // [16]
    float*       out           = (float*)d_out;         // [256,129,129]
    float*       T             = (float*)d_ws;          // 6400 floats used

    hipLaunchKernelGGL(table_kernel, dim3(20), dim3(256), 0, stream, edge_W, dis_W, T);
    hipLaunchKernelGGL(bias_kernel, dim3(EDGE_BLOCKS + BORDER_BLOCKS), dim3(256), 0, stream,
                       spatial_types, spt, spatial_W, graph_token, T, out);
}